// Round 8
// baseline (270.984 us; speedup 1.0000x reference)
//
#include <hip/hip_runtime.h>
#include <hip/hip_bf16.h>
#include <stdint.h>

// ---------------------------------------------------------------------------
// Co-Guiding GAT forward: 2 layers x 4 masked-MHA branches, B=4 N=1024 D=256
// H=8 dk=32.
// R8: attn -12/guard removed (shift-invariant, headroom verified), pointer-
// walk addressing, launch_bounds(256,8), unroll 2.  bf16 O-proj/LN pipeline
// (fp32 intermediates deleted; final residual exact fp32).
// ---------------------------------------------------------------------------

using bf16x8 = __attribute__((ext_vector_type(8))) short;   // 8 bf16 (4 VGPRs)
using f32x4  = __attribute__((ext_vector_type(4))) float;
using f32x16 = __attribute__((ext_vector_type(16))) float;

#define DEVI __device__ __forceinline__

DEVI uint16_t f2bf(float x) {                 // RNE f32 -> bf16 bits
  uint32_t u = __float_as_uint(x);
  u += 0x7FFFu + ((u >> 16) & 1u);
  return (uint16_t)(u >> 16);
}
DEVI uint32_t packbf2(float lo, float hi) {   // hw v_cvt_pk_bf16_f32 via API
  union { __hip_bfloat162 h; uint32_t u; } cv;
  cv.h = __float22bfloat162_rn(make_float2(lo, hi));
  return cv.u;
}
DEVI float bf2f(uint16_t v) { return __uint_as_float((uint32_t)v << 16); }
DEVI int phi4(int m) {                        // swap bits 2<->3 (involution)
  return ((m & 4) << 1) | ((m & 8) >> 1) | (m & 3);
}

// ---------------------------------------------------------------------------
// Weight prep: W[k][n] fp32 -> Wt[n][k] bf16, for 4 types x 8 mats (L*4).
// ---------------------------------------------------------------------------
__global__ __launch_bounds__(256) void wprep_k(const float* __restrict__ Wq,
                                               const float* __restrict__ Wk,
                                               const float* __restrict__ Wv,
                                               const float* __restrict__ Wo,
                                               uint16_t* __restrict__ out) {
  const int z = blockIdx.z;
  const int type = z >> 3, mat = z & 7;
  const float* W = (type == 0 ? Wq : type == 1 ? Wk : type == 2 ? Wv : Wo)
                   + (size_t)mat * 65536;
  uint16_t* o = out + (size_t)type * 524288 + (size_t)mat * 65536;
  const int r0 = blockIdx.y * 64, c0 = blockIdx.x * 64;
  __shared__ float tl[64][68];
  const int t = threadIdx.x;
  {
    const int rr = t >> 2, cb = (t & 3) * 16;
    const float* src = W + (size_t)(r0 + rr) * 256 + c0 + cb;
    #pragma unroll
    for (int q = 0; q < 4; ++q) {
      float4 v = *(const float4*)(src + q * 4);
      tl[rr][cb + q*4 + 0] = v.x; tl[rr][cb + q*4 + 1] = v.y;
      tl[rr][cb + q*4 + 2] = v.z; tl[rr][cb + q*4 + 3] = v.w;
    }
  }
  __syncthreads();
  {
    const int nn = t >> 2, kb = (t & 3) * 16;
    __align__(16) uint16_t tmp[16];
    #pragma unroll
    for (int q = 0; q < 16; ++q) tmp[q] = f2bf(tl[kb + q][nn]);
    uint16_t* dst = o + (size_t)(c0 + nn) * 256 + r0 + kb;
    *(uint4*)&dst[0] = *(uint4*)&tmp[0];
    *(uint4*)&dst[8] = *(uint4*)&tmp[8];
  }
}

// ---------------------------------------------------------------------------
// fp32 -> bf16 copies of layer-0 inputs
// ---------------------------------------------------------------------------
__global__ __launch_bounds__(256) void cvt_k(const float* __restrict__ a,
                                             const float* __restrict__ b,
                                             uint16_t* __restrict__ oa,
                                             uint16_t* __restrict__ ob) {
  const size_t i = ((size_t)blockIdx.x * 256 + threadIdx.x) * 8;
  const float* s = blockIdx.y ? b : a;
  uint16_t* o = blockIdx.y ? ob : oa;
  const float4 f0 = *(const float4*)(s + i), f1 = *(const float4*)(s + i + 4);
  uint4 u;
  u.x = packbf2(f0.x, f0.y); u.y = packbf2(f0.z, f0.w);
  u.z = packbf2(f1.x, f1.y); u.w = packbf2(f1.z, f1.w);
  *(uint4*)(o + i) = u;
}

// ---------------------------------------------------------------------------
// Adjacency -> TRANSPOSED bitmask: adj[b][q][k] -> bits[b][kw][q] (kw = k/32)
// ---------------------------------------------------------------------------
struct AdjArgs { const int* adj[4]; uint32_t* bits[4]; };

__global__ __launch_bounds__(256) void adjbits_k(AdjArgs a) {
  const int* adj = a.adj[blockIdx.z];
  uint32_t* bits = a.bits[blockIdx.z];
  const size_t i = (size_t)blockIdx.x * 256 + threadIdx.x;
  const int lane = threadIdx.x & 63;
  const int v = adj[i];
  unsigned long long m = __ballot(v != 0);
  if ((lane & 31) == 0) {
    const uint32_t wi = (uint32_t)(i >> 5);      // (b*1024+q)*32 + kw
    const uint32_t kw = wi & 31;
    const uint32_t q  = (wi >> 5) & 1023;
    const uint32_t bb = wi >> 15;
    bits[((bb * 32 + kw) << 10) | q] = (uint32_t)(m >> (lane & 32));
  }
}

// ---------------------------------------------------------------------------
// GEMM: C = (Abf[4096][256] @ W[256][256] + bias) * os, epilogue mode per z:
//   mode 1: bf16 [row][col] + bf16 residual add (O-proj)
//   mode 2: bf16 [b][h][n][32] head-major (Q, K)
//   mode 3: bf16 Vt[(b,h)*32+d][1024] with phi-permuted n (V)
// global_load_lds staging, double-buffered, one barrier per 32-K step,
// XOR-swizzled ds_read (source-pre-swizzled; linear LDS dest).
// ---------------------------------------------------------------------------
struct GemmArgs {
  const uint16_t* A[12];
  const uint16_t* W[12];
  const float*    bias[12];
  const uint16_t* res[12];
  void*           C[12];
  float           os[12];
  int             mode[12];
};

DEVI void stage_tile(const uint16_t* __restrict__ Ab,
                     const uint16_t* __restrict__ Wt,
                     int m0, int n0, int kk,
                     char* AsB, char* BsB, int wid, int lane) {
  #pragma unroll
  for (int i = 0; i < 2; ++i) {
    const int seg = i * 4 + wid;                    // 16-row segment 0..7
    const int rl  = (seg << 4) + (lane >> 2);       // linear LDS row
    const int gs  = (lane & 3) ^ ((lane >> 3) & 3); // pre-swizzled src chunk
    const uint16_t* gA = Ab + (size_t)(m0 + rl) * 256 + kk + gs * 8;
    const uint16_t* gB = Wt + (size_t)(n0 + rl) * 256 + kk + gs * 8;
    __builtin_amdgcn_global_load_lds(
        (const __attribute__((address_space(1))) void*)gA,
        (__attribute__((address_space(3))) void*)(AsB + (seg << 10)), 16, 0, 0);
    __builtin_amdgcn_global_load_lds(
        (const __attribute__((address_space(1))) void*)gB,
        (__attribute__((address_space(3))) void*)(BsB + (seg << 10)), 16, 0, 0);
  }
}

__global__ __launch_bounds__(256) void gemm_k(GemmArgs args) {
  const int z  = blockIdx.z;
  const int m0 = blockIdx.y * 128, n0 = blockIdx.x * 128;
  const uint16_t* Ab = args.A[z];
  const uint16_t* Wt = args.W[z];
  __shared__ __align__(16) uint16_t As[2][4096];   // [128][32] per buffer
  __shared__ __align__(16) uint16_t Bs[2][4096];
  const int t = threadIdx.x;
  const int lane = t & 63, wid = t >> 6;
  const int g = lane >> 4, c = lane & 15;
  const int gx = g ^ ((c >> 1) & 3);               // swizzled read chunk
  const int wm = (wid >> 1) * 64, wn = (wid & 1) * 64;
  f32x4 acc[4][4] = {};

  stage_tile(Ab, Wt, m0, n0, 0, (char*)As[0], (char*)Bs[0], wid, lane);
  __syncthreads();

  for (int ks = 0; ks < 8; ++ks) {
    const int buf = ks & 1;
    if (ks < 7)
      stage_tile(Ab, Wt, m0, n0, (ks + 1) * 32,
                 (char*)As[buf ^ 1], (char*)Bs[buf ^ 1], wid, lane);
    bf16x8 af[4], bfr[4];
    #pragma unroll
    for (int mt = 0; mt < 4; ++mt)
      af[mt]  = *(const bf16x8*)&As[buf][(wm + mt * 16 + c) * 32 + gx * 8];
    #pragma unroll
    for (int nt = 0; nt < 4; ++nt)
      bfr[nt] = *(const bf16x8*)&Bs[buf][(wn + nt * 16 + c) * 32 + gx * 8];
    #pragma unroll
    for (int mt = 0; mt < 4; ++mt)
      #pragma unroll
      for (int nt = 0; nt < 4; ++nt)
        acc[mt][nt] = __builtin_amdgcn_mfma_f32_16x16x32_bf16(af[mt], bfr[nt], acc[mt][nt], 0, 0, 0);
    if (ks < 7) __syncthreads();
  }

  const float* bias = args.bias[z];
  const float osz = args.os[z];
  const int mode = args.mode[z];
  float bv[4];
  #pragma unroll
  for (int nt = 0; nt < 4; ++nt) bv[nt] = bias[n0 + wn + nt * 16 + c];

  if (mode == 1) {
    const uint16_t* res = args.res[z];
    uint16_t* C = (uint16_t*)args.C[z];
    #pragma unroll
    for (int mt = 0; mt < 4; ++mt)
      #pragma unroll
      for (int r = 0; r < 4; ++r) {
        const int row = m0 + wm + mt * 16 + 4 * g + r;
        #pragma unroll
        for (int nt = 0; nt < 4; ++nt) {
          const int col = n0 + wn + nt * 16 + c;
          C[(size_t)row * 256 + col] =
              f2bf((acc[mt][nt][r] + bv[nt]) * osz + bf2f(res[(size_t)row * 256 + col]));
        }
      }
  } else if (mode == 2) {
    uint16_t* C = (uint16_t*)args.C[z];
    #pragma unroll
    for (int mt = 0; mt < 4; ++mt)
      #pragma unroll
      for (int r = 0; r < 4; ++r) {
        const int row = m0 + wm + mt * 16 + 4 * g + r;
        const int bb = row >> 10, n = row & 1023;
        #pragma unroll
        for (int nt = 0; nt < 4; ++nt) {
          const int col = n0 + wn + nt * 16 + c;
          const int hh = col >> 5, d = col & 31;
          C[((size_t)(bb * 8 + hh) * 1024 + n) * 32 + d] =
              f2bf((acc[mt][nt][r] + bv[nt]) * osz);
        }
      }
  } else {
    uint16_t* C = (uint16_t*)args.C[z];
    #pragma unroll
    for (int mt = 0; mt < 4; ++mt)
      #pragma unroll
      for (int r = 0; r < 4; ++r) {
        const int row = m0 + wm + mt * 16 + 4 * g + r;
        const int bb = row >> 10, n = row & 1023;
        const int nn = (n & ~15) | phi4(n & 15);
        #pragma unroll
        for (int nt = 0; nt < 4; ++nt) {
          const int col = n0 + wn + nt * 16 + c;
          const int hh = col >> 5, d = col & 31;
          C[((size_t)(bb * 8 + hh) * 32 + d) * 1024 + nn] =
              f2bf((acc[mt][nt][r] + bv[nt]) * osz);
        }
      }
  }
}

// ---------------------------------------------------------------------------
// Fused masked flash attention, 32x32 MFMA, zero-C softmax (shift-free:
// softmax is shift-invariant and this op's score range ~|st|<=20 leaves
// >80 doublings of fp32/bf16 headroom), split-K 2x, pointer-walk loads.
// Lane (c,hi) owns q-row c; st[r]=S[q=c][kk], kk=(r&3)+8*(r>>2)+4*hi.
// pv = v_exp(st)*bit; P packs feed PV directly (Vt phi-permuted at source).
// ---------------------------------------------------------------------------
struct AttnArgs {
  const uint16_t* Q[4];
  const uint16_t* K[4];
  const uint16_t* Vt[4];
  const uint32_t* adjb[4];   // transposed [b][kw][q]
  uint16_t*       O[4];
};

__global__ __launch_bounds__(256, 8) void attn_k(AttnArgs args) {
  const int bid = blockIdx.x;
  const int qt  = bid >> 7;           // 16 q-tiles of 64 rows per group
  const int grp = bid & 127;          // (branch,b,h) -> same XCD
  const int bh = grp & 31, j = grp >> 5;
  const int b = bh >> 3, h = bh & 7;
  const int t = threadIdx.x, wid = t >> 6, lane = t & 63;
  const int qg = wid & 1, ks = wid >> 1;
  const int c = lane & 31, hi = lane >> 5;
  const int hsh = hi * 4;
  const int qrow = qt * 64 + qg * 32 + c;

  const uint16_t* Qbh = args.Q[j] + (size_t)(b * 8 + h) * 32768;
  const uint16_t* Kbh = args.K[j] + (size_t)(b * 8 + h) * 32768;
  const uint16_t* Vbh = args.Vt[j] + ((size_t)(b * 8 + h) * 32 + c) * 1024 + hi * 8;
  const uint32_t* adjT = args.adjb[j] + (size_t)b * 32768 + qrow;

  const bf16x8 qf0 = *(const bf16x8*)&Qbh[qrow * 32 + hi * 8];
  const bf16x8 qf1 = *(const bf16x8*)&Qbh[qrow * 32 + 16 + hi * 8];

  f32x16 oacc = {};
  float l = 0.f;

  const int kbeg = ks * 512;
  const uint16_t* kp = Kbh + (size_t)(kbeg + c) * 32 + hi * 8;
  const uint16_t* vp = Vbh + kbeg;
  const uint32_t* ap = adjT + ((size_t)(kbeg >> 5) << 10);

  #pragma unroll 2
  for (int it = 0; it < 16; ++it) {
    const uint32_t w = (*ap) >> hsh;
    const bf16x8 kf0 = *(const bf16x8*)kp;
    const bf16x8 kf1 = *(const bf16x8*)(kp + 16);
    const bf16x8 vf0 = *(const bf16x8*)vp;         // issued early;
    const bf16x8 vf1 = *(const bf16x8*)(vp + 16);  // used post-softmax
    ap += 1024; kp += 1024; vp += 32;

    f32x16 st = {};
    st = __builtin_amdgcn_mfma_f32_32x32x16_bf16(kf0, qf0, st, 0, 0, 0);
    st = __builtin_amdgcn_mfma_f32_32x32x16_bf16(kf1, qf1, st, 0, 0, 0);

    float s0 = 0.f, s1 = 0.f, s2 = 0.f, s3 = 0.f;
    #pragma unroll
    for (int r = 0; r < 16; ++r) {
      const int pos = (r & 3) + 8 * (r >> 2);   // bit pos (w pre-shifted by hsh)
      const float bitf = (float)((w >> pos) & 1u);
      const float pv = __builtin_amdgcn_exp2f(st[r]) * bitf;  // bare v_exp_f32
      st[r] = pv;
      if ((r & 3) == 0) s0 += pv; else if ((r & 3) == 1) s1 += pv;
      else if ((r & 3) == 2) s2 += pv; else s3 += pv;
    }
    l += (s0 + s1) + (s2 + s3);

    union PU { uint32_t u[4]; bf16x8 v; };
    PU p0, p1;
    p0.u[0] = packbf2(st[0],  st[1]);  p0.u[1] = packbf2(st[2],  st[3]);
    p0.u[2] = packbf2(st[4],  st[5]);  p0.u[3] = packbf2(st[6],  st[7]);
    p1.u[0] = packbf2(st[8],  st[9]);  p1.u[1] = packbf2(st[10], st[11]);
    p1.u[2] = packbf2(st[12], st[13]); p1.u[3] = packbf2(st[14], st[15]);

    oacc = __builtin_amdgcn_mfma_f32_32x32x16_bf16(vf0, p0.v, oacc, 0, 0, 0);
    oacc = __builtin_amdgcn_mfma_f32_32x32x16_bf16(vf1, p1.v, oacc, 0, 0, 0);
  }

  // ---- split-K combine (zero-shift partials add directly) -----------------
  __shared__ float red[2][64][17];
  if (ks == 1) {
    #pragma unroll
    for (int r = 0; r < 16; ++r) red[qg][lane][r] = oacc[r];
    red[qg][lane][16] = l;
  }
  __syncthreads();
  if (ks == 1) return;

  {
    #pragma unroll
    for (int r = 0; r < 16; ++r) oacc[r] += red[qg][lane][r];
    l += red[qg][lane][16];
  }

  l += __shfl_xor(l, 32, 64);
  const float inv = 1.0f / l;
  uint16_t* O = args.O[j];
  const size_t ob = (size_t)(b * 1024 + qrow) * 256 + h * 32 + 4 * hi;
  #pragma unroll
  for (int rq = 0; rq < 4; ++rq) {
    uint2 val;
    val.x = packbf2(oacc[4*rq+0] * inv, oacc[4*rq+1] * inv);
    val.y = packbf2(oacc[4*rq+2] * inv, oacc[4*rq+3] * inv);
    *(uint2*)&O[ob + 8 * rq] = val;
  }
}

// ---------------------------------------------------------------------------
// Fused LayerNorm(x0)+LayerNorm(x1) -> relu(sum) (+ optional fp32 residual).
// x0/x1 bf16.  Writes fp32 out and/or bf16 mirror (either may be null).
// ---------------------------------------------------------------------------
struct LnArgs {
  const uint16_t* x0; const uint16_t* x1;
  const float* g0; const float* be0;
  const float* g1; const float* be1;
  const float* addin;
  float* out;
  uint16_t* outbf;
};
struct LnBoth { LnArgs p[2]; };

__global__ __launch_bounds__(256) void ln_k(LnBoth args) {
  const LnArgs a = args.p[blockIdx.z];
  const int wid = threadIdx.x >> 6, lane = threadIdx.x & 63;
  const int row = blockIdx.x * 4 + wid;
  const size_t off = (size_t)row * 256 + lane * 4;

  const uint2 u0 = *(const uint2*)(a.x0 + off);
  const uint2 u1 = *(const uint2*)(a.x1 + off);
  float4 x0, x1;
  x0.x = bf2f((uint16_t)u0.x); x0.y = bf2f((uint16_t)(u0.x >> 16));
  x0.z = bf2f((uint16_t)u0.y); x0.w = bf2f((uint16_t)(u0.y >> 16));
  x1.x = bf2f((uint16_t)u1.x); x1.y = bf2f((uint16_t)(u1.x >> 16));
  x1.z = bf2f((uint16_t)u1.y); x1.w = bf2f((uint16_t)(u1.y >> 16));

  float s0 = x0.x + x0.y + x0.z + x0.w;
  float s1 = x1.x + x1.y + x1.z + x1.w;
  #pragma unroll
  for (int s = 1; s < 64; s <<= 1) { s0 += __shfl_xor(s0, s, 64); s1 += __shfl_xor(s1, s, 64); }
  const float mu0 = s0 * (1.f / 256.f), mu1 = s1 * (1.f / 256.f);
  const float d0x = x0.x - mu0, d0y = x0.y - mu0, d0z = x0.z - mu0, d0w = x0.w - mu0;
  const float d1x = x1.x - mu1, d1y = x1.y - mu1, d1z = x1.z - mu1, d1w = x1.w - mu1;
  float v0 = d0x * d0x + d0y * d0y + d0z * d0z + d0w * d0w;
  float v1 = d1x * d1x + d1y * d1y + d1z * d1z + d1w * d1w;
  #pragma unroll
  for (int s = 1; s < 64; s <<= 1) { v0 += __shfl_xor(v0, s, 64); v1 += __shfl_xor(v1, s, 64); }
  const float r0 = rsqrtf(v0 * (1.f / 256.f) + 1e-5f);
  const float r1 = rsqrtf(v1 * (1.f / 256.f) + 1e-5f);

  const size_t po = (size_t)lane * 4;
  const float4 g0 = *(const float4*)(a.g0 + po), b0 = *(const float4*)(a.be0 + po);
  const float4 g1 = *(const float4*)(a.g1 + po), b1 = *(const float4*)(a.be1 + po);

  float4 y;
  y.x = fmaxf(d0x * r0 * g0.x + b0.x + d1x * r1 * g1.x + b1.x, 0.f);
  y.y = fmaxf(d0y * r0 * g0.y + b0.y + d1y * r1 * g1.y + b1.y, 0.f);
  y.z = fmaxf(d0z * r0 * g0.z + b0.z + d1z * r1 * g1.z + b1.z, 0.f);
  y.w = fmaxf(d0w * r0 * g0.w + b0.w + d1w * r1 * g1.w + b1.w, 0.f);
  if (a.addin) {
    const float4 ad = *(const float4*)(a.addin + off);
    y.x += ad.x; y.y += ad.y; y.z += ad.z; y.w += ad.w;
  }
  if (a.out) *(float4*)(a.out + off) = y;
  if (a.outbf) {
    uint2 vb;
    vb.x = packbf2(y.x, y.y); vb.y = packbf2(y.z, y.w);
    *(uint2*)(a.outbf + off) = vb;
  }
}

// ---------------------------------------------------------------------------
// Host launch
// ---------------------------------------------------------------------------
extern "C" void kernel_launch(void* const* d_in, const int* in_sizes, int n_in,
                              void* d_out, int out_size, void* d_ws, size_t ws_size,
                              hipStream_t stream) {
  (void)in_sizes; (void)n_in; (void)out_size; (void)ws_size;
  const float* h_a = (const float*)d_in[0];
  const float* h_b = (const float*)d_in[1];
  const float* bq  = (const float*)d_in[7];
  const float* bk  = (const float*)d_in[9];
  const float* bv  = (const float*)d_in[11];
  const float* bo  = (const float*)d_in[13];
  const float* lng = (const float*)d_in[14];
  const float* lnb = (const float*)d_in[15];

  // log2(e)/sqrt(dk): folds softmax scale + exp->exp2 into Q projection
  const float QSC = 1.4426950408889634f * 0.17677669529663687f;

  char* ws = (char*)d_ws;
  uint16_t* WT   = (uint16_t*)ws;                        // 0-4 MB
  uint32_t* ADJB = (uint32_t*)(ws + (4u  << 20));        // 4-6 MB (transposed)
  uint16_t* hAbf = (uint16_t*)(ws + (6u  << 20));        // 6-8 MB
  uint16_t* hBbf = (uint16_t*)(ws + (8u  << 20));        // 8-10 MB
  uint16_t* Qb[4]; uint16_t* Kb[4]; uint16_t* Vtb[4]; uint16_t* ATb[4]; uint16_t* MOb[4];
  for (int j = 0; j < 4; ++j) {
    Qb[j]  = (uint16_t*)(ws + (10u << 20) + (size_t)j * (2u << 20));  // 10-18
    Kb[j]  = (uint16_t*)(ws + (18u << 20) + (size_t)j * (2u << 20));  // 18-26
    Vtb[j] = (uint16_t*)(ws + (26u << 20) + (size_t)j * (2u << 20));  // 26-34
    ATb[j] = (uint16_t*)(ws + (34u << 20) + (size_t)j * (2u << 20));  // 34-42
    MOb[j] = (uint16_t*)(ws + (42u << 20) + (size_t)j * (2u << 20));  // 42-50
  }

  wprep_k<<<dim3(4, 4, 32), 256, 0, stream>>>(
      (const float*)d_in[6], (const float*)d_in[8],
      (const float*)d_in[10], (const float*)d_in[12], WT);
  cvt_k<<<dim3(512, 2), 256, 0, stream>>>(h_a, h_b, hAbf, hBbf);
  {
    AdjArgs aa;
    for (int j = 0; j < 4; ++j) {
      aa.adj[j]  = (const int*)d_in[2 + j];
      aa.bits[j] = ADJB + (size_t)j * 131072;
    }
    adjbits_k<<<dim3(16384, 1, 4), 256, 0, stream>>>(aa);
  }

  for (int i = 0; i < 2; ++i) {
    const uint16_t* qbf[4]  = { hAbf, hBbf, hBbf, hAbf };   // a2a, b2b, a2b, b2a
    const uint16_t* kvbf[4] = { hAbf, hBbf, hAbf, hBbf };

    {
      GemmArgs ga = {};
      for (int j = 0; j < 4; ++j) {
        const int mm = i * 4 + j;
        ga.A[j]     = qbf[j];  ga.W[j]     = WT + 0 * 524288 + (size_t)mm * 65536;
        ga.bias[j]  = bq + mm * 256; ga.C[j] = Qb[j];  ga.os[j] = QSC;  ga.mode[j] = 2;
        ga.A[4+j]   = kvbf[j]; ga.W[4+j]   = WT + 1 * 524288 + (size_t)mm * 65536;
        ga.bias[4+j]= bk + mm * 256; ga.C[4+j] = Kb[j]; ga.os[4+j] = 1.0f; ga.mode[4+j] = 2;
        ga.A[8+j]   = kvbf[j]; ga.W[8+j]   = WT + 2 * 524288 + (size_t)mm * 65536;
        ga.bias[8+j]= bv + mm * 256; ga.C[8+j] = Vtb[j]; ga.os[8+j] = 1.0f; ga.mode[8+j] = 3;
      }
      gemm_k<<<dim3(2, 32, 12), 256, 0, stream>>>(ga);
    }
    {
      AttnArgs at;
      for (int j = 0; j < 4; ++j) {
        at.Q[j] = Qb[j]; at.K[j] = Kb[j]; at.Vt[j] = Vtb[j];
        at.adjb[j] = ADJB + (size_t)j * 131072; at.O[j] = ATb[j];
      }
      attn_k<<<dim3(2048, 1, 1), 256, 0, stream>>>(at);
    }
    {
      GemmArgs go = {};
      for (int j = 0; j < 4; ++j) {
        const int mm = i * 4 + j;
        go.A[j] = ATb[j]; go.W[j] = WT + 3 * 524288 + (size_t)mm * 65536;
        go.bias[j] = bo + mm * 256; go.res[j] = qbf[j]; go.C[j] = MOb[j];
        go.os[j] = 1.0f; go.mode[j] = 1;
      }
      gemm_k<<<dim3(2, 32, 4), 256, 0, stream>>>(go);
    }
    {
      LnBoth lb;
      float* outA = (i == 1) ? (float*)d_out : nullptr;
      float* outB = (i == 1) ? ((float*)d_out + 1048576) : nullptr;
      const float* addA = (i == 1) ? h_a : nullptr;
      const float* addB = (i == 1) ? h_b : nullptr;
      uint16_t* mbA = (i == 0) ? hAbf : nullptr;   // bf16 mirror for next layer
      uint16_t* mbB = (i == 0) ? hBbf : nullptr;
      lb.p[0] = { MOb[0], MOb[3],
                  lng + (i * 4 + 0) * 256, lnb + (i * 4 + 0) * 256,
                  lng + (i * 4 + 3) * 256, lnb + (i * 4 + 3) * 256,
                  addA, outA, mbA };
      lb.p[1] = { MOb[1], MOb[2],
                  lng + (i * 4 + 1) * 256, lnb + (i * 4 + 1) * 256,
                  lng + (i * 4 + 2) * 256, lnb + (i * 4 + 2) * 256,
                  addB, outB, mbB };
      ln_k<<<dim3(1024, 1, 2), 256, 0, stream>>>(lb);
    }
  }
}

// Round 9
// 229.930 us; speedup vs baseline: 1.1785x; 1.1785x over previous
//
#include <hip/hip_runtime.h>
#include <hip/hip_bf16.h>
#include <stdint.h>

// ---------------------------------------------------------------------------
// Co-Guiding GAT forward: 2 layers x 4 masked-MHA branches, B=4 N=1024 D=256
// H=8 dk=32.
// R9: revert R8's launch_bounds(256,8) (VGPR 32 + 70MB scratch spills) and
// unroll-2; keep zero-C softmax, pointer-walk, split-K, bf16 pipeline.
// Mask via sbfe sign-replication + AND on exp bits (2 ops/elem).
// ---------------------------------------------------------------------------

using bf16x8 = __attribute__((ext_vector_type(8))) short;   // 8 bf16 (4 VGPRs)
using f32x4  = __attribute__((ext_vector_type(4))) float;
using f32x16 = __attribute__((ext_vector_type(16))) float;

#define DEVI __device__ __forceinline__

DEVI uint16_t f2bf(float x) {                 // RNE f32 -> bf16 bits
  uint32_t u = __float_as_uint(x);
  u += 0x7FFFu + ((u >> 16) & 1u);
  return (uint16_t)(u >> 16);
}
DEVI uint32_t packbf2(float lo, float hi) {   // hw v_cvt_pk_bf16_f32 via API
  union { __hip_bfloat162 h; uint32_t u; } cv;
  cv.h = __float22bfloat162_rn(make_float2(lo, hi));
  return cv.u;
}
DEVI float bf2f(uint16_t v) { return __uint_as_float((uint32_t)v << 16); }
DEVI int phi4(int m) {                        // swap bits 2<->3 (involution)
  return ((m & 4) << 1) | ((m & 8) >> 1) | (m & 3);
}

// ---------------------------------------------------------------------------
// Weight prep: W[k][n] fp32 -> Wt[n][k] bf16, for 4 types x 8 mats (L*4).
// ---------------------------------------------------------------------------
__global__ __launch_bounds__(256) void wprep_k(const float* __restrict__ Wq,
                                               const float* __restrict__ Wk,
                                               const float* __restrict__ Wv,
                                               const float* __restrict__ Wo,
                                               uint16_t* __restrict__ out) {
  const int z = blockIdx.z;
  const int type = z >> 3, mat = z & 7;
  const float* W = (type == 0 ? Wq : type == 1 ? Wk : type == 2 ? Wv : Wo)
                   + (size_t)mat * 65536;
  uint16_t* o = out + (size_t)type * 524288 + (size_t)mat * 65536;
  const int r0 = blockIdx.y * 64, c0 = blockIdx.x * 64;
  __shared__ float tl[64][68];
  const int t = threadIdx.x;
  {
    const int rr = t >> 2, cb = (t & 3) * 16;
    const float* src = W + (size_t)(r0 + rr) * 256 + c0 + cb;
    #pragma unroll
    for (int q = 0; q < 4; ++q) {
      float4 v = *(const float4*)(src + q * 4);
      tl[rr][cb + q*4 + 0] = v.x; tl[rr][cb + q*4 + 1] = v.y;
      tl[rr][cb + q*4 + 2] = v.z; tl[rr][cb + q*4 + 3] = v.w;
    }
  }
  __syncthreads();
  {
    const int nn = t >> 2, kb = (t & 3) * 16;
    __align__(16) uint16_t tmp[16];
    #pragma unroll
    for (int q = 0; q < 16; ++q) tmp[q] = f2bf(tl[kb + q][nn]);
    uint16_t* dst = o + (size_t)(c0 + nn) * 256 + r0 + kb;
    *(uint4*)&dst[0] = *(uint4*)&tmp[0];
    *(uint4*)&dst[8] = *(uint4*)&tmp[8];
  }
}

// ---------------------------------------------------------------------------
// fp32 -> bf16 copies of layer-0 inputs
// ---------------------------------------------------------------------------
__global__ __launch_bounds__(256) void cvt_k(const float* __restrict__ a,
                                             const float* __restrict__ b,
                                             uint16_t* __restrict__ oa,
                                             uint16_t* __restrict__ ob) {
  const size_t i = ((size_t)blockIdx.x * 256 + threadIdx.x) * 8;
  const float* s = blockIdx.y ? b : a;
  uint16_t* o = blockIdx.y ? ob : oa;
  const float4 f0 = *(const float4*)(s + i), f1 = *(const float4*)(s + i + 4);
  uint4 u;
  u.x = packbf2(f0.x, f0.y); u.y = packbf2(f0.z, f0.w);
  u.z = packbf2(f1.x, f1.y); u.w = packbf2(f1.z, f1.w);
  *(uint4*)(o + i) = u;
}

// ---------------------------------------------------------------------------
// Adjacency -> TRANSPOSED bitmask: adj[b][q][k] -> bits[b][kw][q] (kw = k/32)
// ---------------------------------------------------------------------------
struct AdjArgs { const int* adj[4]; uint32_t* bits[4]; };

__global__ __launch_bounds__(256) void adjbits_k(AdjArgs a) {
  const int* adj = a.adj[blockIdx.z];
  uint32_t* bits = a.bits[blockIdx.z];
  const size_t i = (size_t)blockIdx.x * 256 + threadIdx.x;
  const int lane = threadIdx.x & 63;
  const int v = adj[i];
  unsigned long long m = __ballot(v != 0);
  if ((lane & 31) == 0) {
    const uint32_t wi = (uint32_t)(i >> 5);      // (b*1024+q)*32 + kw
    const uint32_t kw = wi & 31;
    const uint32_t q  = (wi >> 5) & 1023;
    const uint32_t bb = wi >> 15;
    bits[((bb * 32 + kw) << 10) | q] = (uint32_t)(m >> (lane & 32));
  }
}

// ---------------------------------------------------------------------------
// GEMM: C = (Abf[4096][256] @ W[256][256] + bias) * os, epilogue mode per z:
//   mode 1: bf16 [row][col] + bf16 residual add (O-proj)
//   mode 2: bf16 [b][h][n][32] head-major (Q, K)
//   mode 3: bf16 Vt[(b,h)*32+d][1024] with phi-permuted n (V)
// global_load_lds staging, double-buffered, one barrier per 32-K step,
// XOR-swizzled ds_read (source-pre-swizzled; linear LDS dest).
// ---------------------------------------------------------------------------
struct GemmArgs {
  const uint16_t* A[12];
  const uint16_t* W[12];
  const float*    bias[12];
  const uint16_t* res[12];
  void*           C[12];
  float           os[12];
  int             mode[12];
};

DEVI void stage_tile(const uint16_t* __restrict__ Ab,
                     const uint16_t* __restrict__ Wt,
                     int m0, int n0, int kk,
                     char* AsB, char* BsB, int wid, int lane) {
  #pragma unroll
  for (int i = 0; i < 2; ++i) {
    const int seg = i * 4 + wid;                    // 16-row segment 0..7
    const int rl  = (seg << 4) + (lane >> 2);       // linear LDS row
    const int gs  = (lane & 3) ^ ((lane >> 3) & 3); // pre-swizzled src chunk
    const uint16_t* gA = Ab + (size_t)(m0 + rl) * 256 + kk + gs * 8;
    const uint16_t* gB = Wt + (size_t)(n0 + rl) * 256 + kk + gs * 8;
    __builtin_amdgcn_global_load_lds(
        (const __attribute__((address_space(1))) void*)gA,
        (__attribute__((address_space(3))) void*)(AsB + (seg << 10)), 16, 0, 0);
    __builtin_amdgcn_global_load_lds(
        (const __attribute__((address_space(1))) void*)gB,
        (__attribute__((address_space(3))) void*)(BsB + (seg << 10)), 16, 0, 0);
  }
}

__global__ __launch_bounds__(256) void gemm_k(GemmArgs args) {
  const int z  = blockIdx.z;
  const int m0 = blockIdx.y * 128, n0 = blockIdx.x * 128;
  const uint16_t* Ab = args.A[z];
  const uint16_t* Wt = args.W[z];
  __shared__ __align__(16) uint16_t As[2][4096];   // [128][32] per buffer
  __shared__ __align__(16) uint16_t Bs[2][4096];
  const int t = threadIdx.x;
  const int lane = t & 63, wid = t >> 6;
  const int g = lane >> 4, c = lane & 15;
  const int gx = g ^ ((c >> 1) & 3);               // swizzled read chunk
  const int wm = (wid >> 1) * 64, wn = (wid & 1) * 64;
  f32x4 acc[4][4] = {};

  stage_tile(Ab, Wt, m0, n0, 0, (char*)As[0], (char*)Bs[0], wid, lane);
  __syncthreads();

  for (int ks = 0; ks < 8; ++ks) {
    const int buf = ks & 1;
    if (ks < 7)
      stage_tile(Ab, Wt, m0, n0, (ks + 1) * 32,
                 (char*)As[buf ^ 1], (char*)Bs[buf ^ 1], wid, lane);
    bf16x8 af[4], bfr[4];
    #pragma unroll
    for (int mt = 0; mt < 4; ++mt)
      af[mt]  = *(const bf16x8*)&As[buf][(wm + mt * 16 + c) * 32 + gx * 8];
    #pragma unroll
    for (int nt = 0; nt < 4; ++nt)
      bfr[nt] = *(const bf16x8*)&Bs[buf][(wn + nt * 16 + c) * 32 + gx * 8];
    #pragma unroll
    for (int mt = 0; mt < 4; ++mt)
      #pragma unroll
      for (int nt = 0; nt < 4; ++nt)
        acc[mt][nt] = __builtin_amdgcn_mfma_f32_16x16x32_bf16(af[mt], bfr[nt], acc[mt][nt], 0, 0, 0);
    if (ks < 7) __syncthreads();
  }

  const float* bias = args.bias[z];
  const float osz = args.os[z];
  const int mode = args.mode[z];
  float bv[4];
  #pragma unroll
  for (int nt = 0; nt < 4; ++nt) bv[nt] = bias[n0 + wn + nt * 16 + c];

  if (mode == 1) {
    const uint16_t* res = args.res[z];
    uint16_t* C = (uint16_t*)args.C[z];
    #pragma unroll
    for (int mt = 0; mt < 4; ++mt)
      #pragma unroll
      for (int r = 0; r < 4; ++r) {
        const int row = m0 + wm + mt * 16 + 4 * g + r;
        #pragma unroll
        for (int nt = 0; nt < 4; ++nt) {
          const int col = n0 + wn + nt * 16 + c;
          C[(size_t)row * 256 + col] =
              f2bf((acc[mt][nt][r] + bv[nt]) * osz + bf2f(res[(size_t)row * 256 + col]));
        }
      }
  } else if (mode == 2) {
    uint16_t* C = (uint16_t*)args.C[z];
    #pragma unroll
    for (int mt = 0; mt < 4; ++mt)
      #pragma unroll
      for (int r = 0; r < 4; ++r) {
        const int row = m0 + wm + mt * 16 + 4 * g + r;
        const int bb = row >> 10, n = row & 1023;
        #pragma unroll
        for (int nt = 0; nt < 4; ++nt) {
          const int col = n0 + wn + nt * 16 + c;
          const int hh = col >> 5, d = col & 31;
          C[((size_t)(bb * 8 + hh) * 1024 + n) * 32 + d] =
              f2bf((acc[mt][nt][r] + bv[nt]) * osz);
        }
      }
  } else {
    uint16_t* C = (uint16_t*)args.C[z];
    #pragma unroll
    for (int mt = 0; mt < 4; ++mt)
      #pragma unroll
      for (int r = 0; r < 4; ++r) {
        const int row = m0 + wm + mt * 16 + 4 * g + r;
        const int bb = row >> 10, n = row & 1023;
        const int nn = (n & ~15) | phi4(n & 15);
        #pragma unroll
        for (int nt = 0; nt < 4; ++nt) {
          const int col = n0 + wn + nt * 16 + c;
          const int hh = col >> 5, d = col & 31;
          C[((size_t)(bb * 8 + hh) * 32 + d) * 1024 + nn] =
              f2bf((acc[mt][nt][r] + bv[nt]) * osz);
        }
      }
  }
}

// ---------------------------------------------------------------------------
// Fused masked flash attention, 32x32 MFMA, zero-C softmax (shift-free),
// split-K 2x, pointer-walk loads.  Lane (c,hi) owns q-row c;
// st[r]=S[q=c][kk], kk=(r&3)+8*(r>>2)+4*hi.  Mask: sbfe sign-replicated bit
// AND'ed onto exp bits (masked -> +0.0f).  P packs feed PV directly
// (Vt phi-permuted at source).
// ---------------------------------------------------------------------------
struct AttnArgs {
  const uint16_t* Q[4];
  const uint16_t* K[4];
  const uint16_t* Vt[4];
  const uint32_t* adjb[4];   // transposed [b][kw][q]
  uint16_t*       O[4];
};

__global__ __launch_bounds__(256) void attn_k(AttnArgs args) {
  const int bid = blockIdx.x;
  const int qt  = bid >> 7;           // 16 q-tiles of 64 rows per group
  const int grp = bid & 127;          // (branch,b,h) -> same XCD
  const int bh = grp & 31, j = grp >> 5;
  const int b = bh >> 3, h = bh & 7;
  const int t = threadIdx.x, wid = t >> 6, lane = t & 63;
  const int qg = wid & 1, ks = wid >> 1;
  const int c = lane & 31, hi = lane >> 5;
  const int hsh = hi * 4;
  const int qrow = qt * 64 + qg * 32 + c;

  const uint16_t* Qbh = args.Q[j] + (size_t)(b * 8 + h) * 32768;
  const uint16_t* Kbh = args.K[j] + (size_t)(b * 8 + h) * 32768;
  const uint16_t* Vbh = args.Vt[j] + ((size_t)(b * 8 + h) * 32 + c) * 1024 + hi * 8;
  const uint32_t* adjT = args.adjb[j] + (size_t)b * 32768 + qrow;

  const bf16x8 qf0 = *(const bf16x8*)&Qbh[qrow * 32 + hi * 8];
  const bf16x8 qf1 = *(const bf16x8*)&Qbh[qrow * 32 + 16 + hi * 8];

  f32x16 oacc = {};
  float l = 0.f;

  const int kbeg = ks * 512;
  const uint16_t* kp = Kbh + (size_t)(kbeg + c) * 32 + hi * 8;
  const uint16_t* vp = Vbh + kbeg;
  const uint32_t* ap = adjT + ((size_t)(kbeg >> 5) << 10);

  for (int it = 0; it < 16; ++it) {
    const uint32_t w = (*ap) >> hsh;
    const bf16x8 kf0 = *(const bf16x8*)kp;
    const bf16x8 kf1 = *(const bf16x8*)(kp + 16);
    const bf16x8 vf0 = *(const bf16x8*)vp;         // issued early;
    const bf16x8 vf1 = *(const bf16x8*)(vp + 16);  // used post-softmax
    ap += 1024; kp += 1024; vp += 32;

    f32x16 st = {};
    st = __builtin_amdgcn_mfma_f32_32x32x16_bf16(kf0, qf0, st, 0, 0, 0);
    st = __builtin_amdgcn_mfma_f32_32x32x16_bf16(kf1, qf1, st, 0, 0, 0);

    float s0 = 0.f, s1 = 0.f, s2 = 0.f, s3 = 0.f;
    #pragma unroll
    for (int r = 0; r < 16; ++r) {
      const int pos = (r & 3) + 8 * (r >> 2);   // bit pos (w pre-shifted by hsh)
      // sign-replicate bit -> 0 / 0xFFFFFFFF, AND onto exp bits (masked -> +0)
      const uint32_t msk = (uint32_t)__builtin_amdgcn_sbfe((int)w, pos, 1);
      const float pv = __uint_as_float(
          __float_as_uint(__builtin_amdgcn_exp2f(st[r])) & msk);
      st[r] = pv;
      if ((r & 3) == 0) s0 += pv; else if ((r & 3) == 1) s1 += pv;
      else if ((r & 3) == 2) s2 += pv; else s3 += pv;
    }
    l += (s0 + s1) + (s2 + s3);

    union PU { uint32_t u[4]; bf16x8 v; };
    PU p0, p1;
    p0.u[0] = packbf2(st[0],  st[1]);  p0.u[1] = packbf2(st[2],  st[3]);
    p0.u[2] = packbf2(st[4],  st[5]);  p0.u[3] = packbf2(st[6],  st[7]);
    p1.u[0] = packbf2(st[8],  st[9]);  p1.u[1] = packbf2(st[10], st[11]);
    p1.u[2] = packbf2(st[12], st[13]); p1.u[3] = packbf2(st[14], st[15]);

    oacc = __builtin_amdgcn_mfma_f32_32x32x16_bf16(vf0, p0.v, oacc, 0, 0, 0);
    oacc = __builtin_amdgcn_mfma_f32_32x32x16_bf16(vf1, p1.v, oacc, 0, 0, 0);
  }

  // ---- split-K combine (zero-shift partials add directly) -----------------
  __shared__ float red[2][64][17];
  if (ks == 1) {
    #pragma unroll
    for (int r = 0; r < 16; ++r) red[qg][lane][r] = oacc[r];
    red[qg][lane][16] = l;
  }
  __syncthreads();
  if (ks == 1) return;

  {
    #pragma unroll
    for (int r = 0; r < 16; ++r) oacc[r] += red[qg][lane][r];
    l += red[qg][lane][16];
  }

  l += __shfl_xor(l, 32, 64);
  const float inv = 1.0f / l;
  uint16_t* O = args.O[j];
  const size_t ob = (size_t)(b * 1024 + qrow) * 256 + h * 32 + 4 * hi;
  #pragma unroll
  for (int rq = 0; rq < 4; ++rq) {
    uint2 val;
    val.x = packbf2(oacc[4*rq+0] * inv, oacc[4*rq+1] * inv);
    val.y = packbf2(oacc[4*rq+2] * inv, oacc[4*rq+3] * inv);
    *(uint2*)&O[ob + 8 * rq] = val;
  }
}

// ---------------------------------------------------------------------------
// Fused LayerNorm(x0)+LayerNorm(x1) -> relu(sum) (+ optional fp32 residual).
// x0/x1 bf16.  Writes fp32 out and/or bf16 mirror (either may be null).
// ---------------------------------------------------------------------------
struct LnArgs {
  const uint16_t* x0; const uint16_t* x1;
  const float* g0; const float* be0;
  const float* g1; const float* be1;
  const float* addin;
  float* out;
  uint16_t* outbf;
};
struct LnBoth { LnArgs p[2]; };

__global__ __launch_bounds__(256) void ln_k(LnBoth args) {
  const LnArgs a = args.p[blockIdx.z];
  const int wid = threadIdx.x >> 6, lane = threadIdx.x & 63;
  const int row = blockIdx.x * 4 + wid;
  const size_t off = (size_t)row * 256 + lane * 4;

  const uint2 u0 = *(const uint2*)(a.x0 + off);
  const uint2 u1 = *(const uint2*)(a.x1 + off);
  float4 x0, x1;
  x0.x = bf2f((uint16_t)u0.x); x0.y = bf2f((uint16_t)(u0.x >> 16));
  x0.z = bf2f((uint16_t)u0.y); x0.w = bf2f((uint16_t)(u0.y >> 16));
  x1.x = bf2f((uint16_t)u1.x); x1.y = bf2f((uint16_t)(u1.x >> 16));
  x1.z = bf2f((uint16_t)u1.y); x1.w = bf2f((uint16_t)(u1.y >> 16));

  float s0 = x0.x + x0.y + x0.z + x0.w;
  float s1 = x1.x + x1.y + x1.z + x1.w;
  #pragma unroll
  for (int s = 1; s < 64; s <<= 1) { s0 += __shfl_xor(s0, s, 64); s1 += __shfl_xor(s1, s, 64); }
  const float mu0 = s0 * (1.f / 256.f), mu1 = s1 * (1.f / 256.f);
  const float d0x = x0.x - mu0, d0y = x0.y - mu0, d0z = x0.z - mu0, d0w = x0.w - mu0;
  const float d1x = x1.x - mu1, d1y = x1.y - mu1, d1z = x1.z - mu1, d1w = x1.w - mu1;
  float v0 = d0x * d0x + d0y * d0y + d0z * d0z + d0w * d0w;
  float v1 = d1x * d1x + d1y * d1y + d1z * d1z + d1w * d1w;
  #pragma unroll
  for (int s = 1; s < 64; s <<= 1) { v0 += __shfl_xor(v0, s, 64); v1 += __shfl_xor(v1, s, 64); }
  const float r0 = rsqrtf(v0 * (1.f / 256.f) + 1e-5f);
  const float r1 = rsqrtf(v1 * (1.f / 256.f) + 1e-5f);

  const size_t po = (size_t)lane * 4;
  const float4 g0 = *(const float4*)(a.g0 + po), b0 = *(const float4*)(a.be0 + po);
  const float4 g1 = *(const float4*)(a.g1 + po), b1 = *(const float4*)(a.be1 + po);

  float4 y;
  y.x = fmaxf(d0x * r0 * g0.x + b0.x + d1x * r1 * g1.x + b1.x, 0.f);
  y.y = fmaxf(d0y * r0 * g0.y + b0.y + d1y * r1 * g1.y + b1.y, 0.f);
  y.z = fmaxf(d0z * r0 * g0.z + b0.z + d1z * r1 * g1.z + b1.z, 0.f);
  y.w = fmaxf(d0w * r0 * g0.w + b0.w + d1w * r1 * g1.w + b1.w, 0.f);
  if (a.addin) {
    const float4 ad = *(const float4*)(a.addin + off);
    y.x += ad.x; y.y += ad.y; y.z += ad.z; y.w += ad.w;
  }
  if (a.out) *(float4*)(a.out + off) = y;
  if (a.outbf) {
    uint2 vb;
    vb.x = packbf2(y.x, y.y); vb.y = packbf2(y.z, y.w);
    *(uint2*)(a.outbf + off) = vb;
  }
}

// ---------------------------------------------------------------------------
// Host launch
// ---------------------------------------------------------------------------
extern "C" void kernel_launch(void* const* d_in, const int* in_sizes, int n_in,
                              void* d_out, int out_size, void* d_ws, size_t ws_size,
                              hipStream_t stream) {
  (void)in_sizes; (void)n_in; (void)out_size; (void)ws_size;
  const float* h_a = (const float*)d_in[0];
  const float* h_b = (const float*)d_in[1];
  const float* bq  = (const float*)d_in[7];
  const float* bk  = (const float*)d_in[9];
  const float* bv  = (const float*)d_in[11];
  const float* bo  = (const float*)d_in[13];
  const float* lng = (const float*)d_in[14];
  const float* lnb = (const float*)d_in[15];

  // log2(e)/sqrt(dk): folds softmax scale + exp->exp2 into Q projection
  const float QSC = 1.4426950408889634f * 0.17677669529663687f;

  char* ws = (char*)d_ws;
  uint16_t* WT   = (uint16_t*)ws;                        // 0-4 MB
  uint32_t* ADJB = (uint32_t*)(ws + (4u  << 20));        // 4-6 MB (transposed)
  uint16_t* hAbf = (uint16_t*)(ws + (6u  << 20));        // 6-8 MB
  uint16_t* hBbf = (uint16_t*)(ws + (8u  << 20));        // 8-10 MB
  uint16_t* Qb[4]; uint16_t* Kb[4]; uint16_t* Vtb[4]; uint16_t* ATb[4]; uint16_t* MOb[4];
  for (int j = 0; j < 4; ++j) {
    Qb[j]  = (uint16_t*)(ws + (10u << 20) + (size_t)j * (2u << 20));  // 10-18
    Kb[j]  = (uint16_t*)(ws + (18u << 20) + (size_t)j * (2u << 20));  // 18-26
    Vtb[j] = (uint16_t*)(ws + (26u << 20) + (size_t)j * (2u << 20));  // 26-34
    ATb[j] = (uint16_t*)(ws + (34u << 20) + (size_t)j * (2u << 20));  // 34-42
    MOb[j] = (uint16_t*)(ws + (42u << 20) + (size_t)j * (2u << 20));  // 42-50
  }

  wprep_k<<<dim3(4, 4, 32), 256, 0, stream>>>(
      (const float*)d_in[6], (const float*)d_in[8],
      (const float*)d_in[10], (const float*)d_in[12], WT);
  cvt_k<<<dim3(512, 2), 256, 0, stream>>>(h_a, h_b, hAbf, hBbf);
  {
    AdjArgs aa;
    for (int j = 0; j < 4; ++j) {
      aa.adj[j]  = (const int*)d_in[2 + j];
      aa.bits[j] = ADJB + (size_t)j * 131072;
    }
    adjbits_k<<<dim3(16384, 1, 4), 256, 0, stream>>>(aa);
  }

  for (int i = 0; i < 2; ++i) {
    const uint16_t* qbf[4]  = { hAbf, hBbf, hBbf, hAbf };   // a2a, b2b, a2b, b2a
    const uint16_t* kvbf[4] = { hAbf, hBbf, hAbf, hBbf };

    {
      GemmArgs ga = {};
      for (int j = 0; j < 4; ++j) {
        const int mm = i * 4 + j;
        ga.A[j]     = qbf[j];  ga.W[j]     = WT + 0 * 524288 + (size_t)mm * 65536;
        ga.bias[j]  = bq + mm * 256; ga.C[j] = Qb[j];  ga.os[j] = QSC;  ga.mode[j] = 2;
        ga.A[4+j]   = kvbf[j]; ga.W[4+j]   = WT + 1 * 524288 + (size_t)mm * 65536;
        ga.bias[4+j]= bk + mm * 256; ga.C[4+j] = Kb[j]; ga.os[4+j] = 1.0f; ga.mode[4+j] = 2;
        ga.A[8+j]   = kvbf[j]; ga.W[8+j]   = WT + 2 * 524288 + (size_t)mm * 65536;
        ga.bias[8+j]= bv + mm * 256; ga.C[8+j] = Vtb[j]; ga.os[8+j] = 1.0f; ga.mode[8+j] = 3;
      }
      gemm_k<<<dim3(2, 32, 12), 256, 0, stream>>>(ga);
    }
    {
      AttnArgs at;
      for (int j = 0; j < 4; ++j) {
        at.Q[j] = Qb[j]; at.K[j] = Kb[j]; at.Vt[j] = Vtb[j];
        at.adjb[j] = ADJB + (size_t)j * 131072; at.O[j] = ATb[j];
      }
      attn_k<<<dim3(2048, 1, 1), 256, 0, stream>>>(at);
    }
    {
      GemmArgs go = {};
      for (int j = 0; j < 4; ++j) {
        const int mm = i * 4 + j;
        go.A[j] = ATb[j]; go.W[j] = WT + 3 * 524288 + (size_t)mm * 65536;
        go.bias[j] = bo + mm * 256; go.res[j] = qbf[j]; go.C[j] = MOb[j];
        go.os[j] = 1.0f; go.mode[j] = 1;
      }
      gemm_k<<<dim3(2, 32, 4), 256, 0, stream>>>(go);
    }
    {
      LnBoth lb;
      float* outA = (i == 1) ? (float*)d_out : nullptr;
      float* outB = (i == 1) ? ((float*)d_out + 1048576) : nullptr;
      const float* addA = (i == 1) ? h_a : nullptr;
      const float* addB = (i == 1) ? h_b : nullptr;
      uint16_t* mbA = (i == 0) ? hAbf : nullptr;   // bf16 mirror for next layer
      uint16_t* mbB = (i == 0) ? hBbf : nullptr;
      lb.p[0] = { MOb[0], MOb[3],
                  lng + (i * 4 + 0) * 256, lnb + (i * 4 + 0) * 256,
                  lng + (i * 4 + 3) * 256, lnb + (i * 4 + 3) * 256,
                  addA, outA, mbA };
      lb.p[1] = { MOb[1], MOb[2],
                  lng + (i * 4 + 1) * 256, lnb + (i * 4 + 1) * 256,
                  lng + (i * 4 + 2) * 256, lnb + (i * 4 + 2) * 256,
                  addB, outB, mbB };
      ln_k<<<dim3(1024, 1, 2), 256, 0, stream>>>(lb);
    }
  }
}

// Round 10
// 200.581 us; speedup vs baseline: 1.3510x; 1.1463x over previous
//
#include <hip/hip_runtime.h>
#include <hip/hip_bf16.h>
#include <stdint.h>

// ---------------------------------------------------------------------------
// Co-Guiding GAT forward: 2 layers x 4 masked-MHA branches, B=4 N=1024 D=256
// H=8 dk=32.
// R10: attn processes TWO 32x32 q-tiles per wave sharing one K/V load stream
// (halves per-iteration fixed cost; doubles independent softmax ILP).
// Grid 1024 blocks, split-K 2 kept.  Rest identical to R9.
// ---------------------------------------------------------------------------

using bf16x8 = __attribute__((ext_vector_type(8))) short;   // 8 bf16 (4 VGPRs)
using f32x4  = __attribute__((ext_vector_type(4))) float;
using f32x16 = __attribute__((ext_vector_type(16))) float;

#define DEVI __device__ __forceinline__

DEVI uint16_t f2bf(float x) {                 // RNE f32 -> bf16 bits
  uint32_t u = __float_as_uint(x);
  u += 0x7FFFu + ((u >> 16) & 1u);
  return (uint16_t)(u >> 16);
}
DEVI uint32_t packbf2(float lo, float hi) {   // hw v_cvt_pk_bf16_f32 via API
  union { __hip_bfloat162 h; uint32_t u; } cv;
  cv.h = __float22bfloat162_rn(make_float2(lo, hi));
  return cv.u;
}
DEVI float bf2f(uint16_t v) { return __uint_as_float((uint32_t)v << 16); }
DEVI int phi4(int m) {                        // swap bits 2<->3 (involution)
  return ((m & 4) << 1) | ((m & 8) >> 1) | (m & 3);
}

// ---------------------------------------------------------------------------
// Weight prep: W[k][n] fp32 -> Wt[n][k] bf16, for 4 types x 8 mats (L*4).
// ---------------------------------------------------------------------------
__global__ __launch_bounds__(256) void wprep_k(const float* __restrict__ Wq,
                                               const float* __restrict__ Wk,
                                               const float* __restrict__ Wv,
                                               const float* __restrict__ Wo,
                                               uint16_t* __restrict__ out) {
  const int z = blockIdx.z;
  const int type = z >> 3, mat = z & 7;
  const float* W = (type == 0 ? Wq : type == 1 ? Wk : type == 2 ? Wv : Wo)
                   + (size_t)mat * 65536;
  uint16_t* o = out + (size_t)type * 524288 + (size_t)mat * 65536;
  const int r0 = blockIdx.y * 64, c0 = blockIdx.x * 64;
  __shared__ float tl[64][68];
  const int t = threadIdx.x;
  {
    const int rr = t >> 2, cb = (t & 3) * 16;
    const float* src = W + (size_t)(r0 + rr) * 256 + c0 + cb;
    #pragma unroll
    for (int q = 0; q < 4; ++q) {
      float4 v = *(const float4*)(src + q * 4);
      tl[rr][cb + q*4 + 0] = v.x; tl[rr][cb + q*4 + 1] = v.y;
      tl[rr][cb + q*4 + 2] = v.z; tl[rr][cb + q*4 + 3] = v.w;
    }
  }
  __syncthreads();
  {
    const int nn = t >> 2, kb = (t & 3) * 16;
    __align__(16) uint16_t tmp[16];
    #pragma unroll
    for (int q = 0; q < 16; ++q) tmp[q] = f2bf(tl[kb + q][nn]);
    uint16_t* dst = o + (size_t)(c0 + nn) * 256 + r0 + kb;
    *(uint4*)&dst[0] = *(uint4*)&tmp[0];
    *(uint4*)&dst[8] = *(uint4*)&tmp[8];
  }
}

// ---------------------------------------------------------------------------
// fp32 -> bf16 copies of layer-0 inputs
// ---------------------------------------------------------------------------
__global__ __launch_bounds__(256) void cvt_k(const float* __restrict__ a,
                                             const float* __restrict__ b,
                                             uint16_t* __restrict__ oa,
                                             uint16_t* __restrict__ ob) {
  const size_t i = ((size_t)blockIdx.x * 256 + threadIdx.x) * 8;
  const float* s = blockIdx.y ? b : a;
  uint16_t* o = blockIdx.y ? ob : oa;
  const float4 f0 = *(const float4*)(s + i), f1 = *(const float4*)(s + i + 4);
  uint4 u;
  u.x = packbf2(f0.x, f0.y); u.y = packbf2(f0.z, f0.w);
  u.z = packbf2(f1.x, f1.y); u.w = packbf2(f1.z, f1.w);
  *(uint4*)(o + i) = u;
}

// ---------------------------------------------------------------------------
// Adjacency -> TRANSPOSED bitmask: adj[b][q][k] -> bits[b][kw][q] (kw = k/32)
// ---------------------------------------------------------------------------
struct AdjArgs { const int* adj[4]; uint32_t* bits[4]; };

__global__ __launch_bounds__(256) void adjbits_k(AdjArgs a) {
  const int* adj = a.adj[blockIdx.z];
  uint32_t* bits = a.bits[blockIdx.z];
  const size_t i = (size_t)blockIdx.x * 256 + threadIdx.x;
  const int lane = threadIdx.x & 63;
  const int v = adj[i];
  unsigned long long m = __ballot(v != 0);
  if ((lane & 31) == 0) {
    const uint32_t wi = (uint32_t)(i >> 5);      // (b*1024+q)*32 + kw
    const uint32_t kw = wi & 31;
    const uint32_t q  = (wi >> 5) & 1023;
    const uint32_t bb = wi >> 15;
    bits[((bb * 32 + kw) << 10) | q] = (uint32_t)(m >> (lane & 32));
  }
}

// ---------------------------------------------------------------------------
// GEMM: C = (Abf[4096][256] @ W[256][256] + bias) * os, epilogue mode per z:
//   mode 1: bf16 [row][col] + bf16 residual add (O-proj)
//   mode 2: bf16 [b][h][n][32] head-major (Q, K)
//   mode 3: bf16 Vt[(b,h)*32+d][1024] with phi-permuted n (V)
// global_load_lds staging, double-buffered, one barrier per 32-K step,
// XOR-swizzled ds_read (source-pre-swizzled; linear LDS dest).
// ---------------------------------------------------------------------------
struct GemmArgs {
  const uint16_t* A[12];
  const uint16_t* W[12];
  const float*    bias[12];
  const uint16_t* res[12];
  void*           C[12];
  float           os[12];
  int             mode[12];
};

DEVI void stage_tile(const uint16_t* __restrict__ Ab,
                     const uint16_t* __restrict__ Wt,
                     int m0, int n0, int kk,
                     char* AsB, char* BsB, int wid, int lane) {
  #pragma unroll
  for (int i = 0; i < 2; ++i) {
    const int seg = i * 4 + wid;                    // 16-row segment 0..7
    const int rl  = (seg << 4) + (lane >> 2);       // linear LDS row
    const int gs  = (lane & 3) ^ ((lane >> 3) & 3); // pre-swizzled src chunk
    const uint16_t* gA = Ab + (size_t)(m0 + rl) * 256 + kk + gs * 8;
    const uint16_t* gB = Wt + (size_t)(n0 + rl) * 256 + kk + gs * 8;
    __builtin_amdgcn_global_load_lds(
        (const __attribute__((address_space(1))) void*)gA,
        (__attribute__((address_space(3))) void*)(AsB + (seg << 10)), 16, 0, 0);
    __builtin_amdgcn_global_load_lds(
        (const __attribute__((address_space(1))) void*)gB,
        (__attribute__((address_space(3))) void*)(BsB + (seg << 10)), 16, 0, 0);
  }
}

__global__ __launch_bounds__(256) void gemm_k(GemmArgs args) {
  const int z  = blockIdx.z;
  const int m0 = blockIdx.y * 128, n0 = blockIdx.x * 128;
  const uint16_t* Ab = args.A[z];
  const uint16_t* Wt = args.W[z];
  __shared__ __align__(16) uint16_t As[2][4096];   // [128][32] per buffer
  __shared__ __align__(16) uint16_t Bs[2][4096];
  const int t = threadIdx.x;
  const int lane = t & 63, wid = t >> 6;
  const int g = lane >> 4, c = lane & 15;
  const int gx = g ^ ((c >> 1) & 3);               // swizzled read chunk
  const int wm = (wid >> 1) * 64, wn = (wid & 1) * 64;
  f32x4 acc[4][4] = {};

  stage_tile(Ab, Wt, m0, n0, 0, (char*)As[0], (char*)Bs[0], wid, lane);
  __syncthreads();

  for (int ks = 0; ks < 8; ++ks) {
    const int buf = ks & 1;
    if (ks < 7)
      stage_tile(Ab, Wt, m0, n0, (ks + 1) * 32,
                 (char*)As[buf ^ 1], (char*)Bs[buf ^ 1], wid, lane);
    bf16x8 af[4], bfr[4];
    #pragma unroll
    for (int mt = 0; mt < 4; ++mt)
      af[mt]  = *(const bf16x8*)&As[buf][(wm + mt * 16 + c) * 32 + gx * 8];
    #pragma unroll
    for (int nt = 0; nt < 4; ++nt)
      bfr[nt] = *(const bf16x8*)&Bs[buf][(wn + nt * 16 + c) * 32 + gx * 8];
    #pragma unroll
    for (int mt = 0; mt < 4; ++mt)
      #pragma unroll
      for (int nt = 0; nt < 4; ++nt)
        acc[mt][nt] = __builtin_amdgcn_mfma_f32_16x16x32_bf16(af[mt], bfr[nt], acc[mt][nt], 0, 0, 0);
    if (ks < 7) __syncthreads();
  }

  const float* bias = args.bias[z];
  const float osz = args.os[z];
  const int mode = args.mode[z];
  float bv[4];
  #pragma unroll
  for (int nt = 0; nt < 4; ++nt) bv[nt] = bias[n0 + wn + nt * 16 + c];

  if (mode == 1) {
    const uint16_t* res = args.res[z];
    uint16_t* C = (uint16_t*)args.C[z];
    #pragma unroll
    for (int mt = 0; mt < 4; ++mt)
      #pragma unroll
      for (int r = 0; r < 4; ++r) {
        const int row = m0 + wm + mt * 16 + 4 * g + r;
        #pragma unroll
        for (int nt = 0; nt < 4; ++nt) {
          const int col = n0 + wn + nt * 16 + c;
          C[(size_t)row * 256 + col] =
              f2bf((acc[mt][nt][r] + bv[nt]) * osz + bf2f(res[(size_t)row * 256 + col]));
        }
      }
  } else if (mode == 2) {
    uint16_t* C = (uint16_t*)args.C[z];
    #pragma unroll
    for (int mt = 0; mt < 4; ++mt)
      #pragma unroll
      for (int r = 0; r < 4; ++r) {
        const int row = m0 + wm + mt * 16 + 4 * g + r;
        const int bb = row >> 10, n = row & 1023;
        #pragma unroll
        for (int nt = 0; nt < 4; ++nt) {
          const int col = n0 + wn + nt * 16 + c;
          const int hh = col >> 5, d = col & 31;
          C[((size_t)(bb * 8 + hh) * 1024 + n) * 32 + d] =
              f2bf((acc[mt][nt][r] + bv[nt]) * osz);
        }
      }
  } else {
    uint16_t* C = (uint16_t*)args.C[z];
    #pragma unroll
    for (int mt = 0; mt < 4; ++mt)
      #pragma unroll
      for (int r = 0; r < 4; ++r) {
        const int row = m0 + wm + mt * 16 + 4 * g + r;
        const int bb = row >> 10, n = row & 1023;
        const int nn = (n & ~15) | phi4(n & 15);
        #pragma unroll
        for (int nt = 0; nt < 4; ++nt) {
          const int col = n0 + wn + nt * 16 + c;
          const int hh = col >> 5, d = col & 31;
          C[((size_t)(bb * 8 + hh) * 32 + d) * 1024 + nn] =
              f2bf((acc[mt][nt][r] + bv[nt]) * osz);
        }
      }
  }
}

// ---------------------------------------------------------------------------
// Fused masked flash attention, 32x32 MFMA, zero-C softmax, split-K 2x,
// TWO q-tiles per wave sharing one K/V stream.
// Lane (c,hi) owns q-rows qrow (tile A) and qrow+32 (tile B);
// st[r]=S[q=c][kk], kk=(r&3)+8*(r>>2)+4*hi.  Mask: sbfe sign-replicated bit
// AND'ed onto exp bits.  P packs feed PV directly (Vt phi-permuted at source).
// ---------------------------------------------------------------------------
struct AttnArgs {
  const uint16_t* Q[4];
  const uint16_t* K[4];
  const uint16_t* Vt[4];
  const uint32_t* adjb[4];   // transposed [b][kw][q]
  uint16_t*       O[4];
};

DEVI void soft_pv(f32x16& st, uint32_t w, float& l,
                  const bf16x8& vf0, const bf16x8& vf1, f32x16& oacc) {
  float s0 = 0.f, s1 = 0.f, s2 = 0.f, s3 = 0.f;
  #pragma unroll
  for (int r = 0; r < 16; ++r) {
    const int pos = (r & 3) + 8 * (r >> 2);
    const uint32_t msk = (uint32_t)__builtin_amdgcn_sbfe((int)w, pos, 1);
    const float pv = __uint_as_float(
        __float_as_uint(__builtin_amdgcn_exp2f(st[r])) & msk);
    st[r] = pv;
    if ((r & 3) == 0) s0 += pv; else if ((r & 3) == 1) s1 += pv;
    else if ((r & 3) == 2) s2 += pv; else s3 += pv;
  }
  l += (s0 + s1) + (s2 + s3);

  union PU { uint32_t u[4]; bf16x8 v; };
  PU p0, p1;
  p0.u[0] = packbf2(st[0],  st[1]);  p0.u[1] = packbf2(st[2],  st[3]);
  p0.u[2] = packbf2(st[4],  st[5]);  p0.u[3] = packbf2(st[6],  st[7]);
  p1.u[0] = packbf2(st[8],  st[9]);  p1.u[1] = packbf2(st[10], st[11]);
  p1.u[2] = packbf2(st[12], st[13]); p1.u[3] = packbf2(st[14], st[15]);

  oacc = __builtin_amdgcn_mfma_f32_32x32x16_bf16(vf0, p0.v, oacc, 0, 0, 0);
  oacc = __builtin_amdgcn_mfma_f32_32x32x16_bf16(vf1, p1.v, oacc, 0, 0, 0);
}

__global__ __launch_bounds__(256) void attn_k(AttnArgs args) {
  const int bid = blockIdx.x;
  const int qt  = bid >> 7;           // 8 q-tiles of 128 rows per group
  const int grp = bid & 127;          // (branch,b,h) -> same XCD
  const int bh = grp & 31, j = grp >> 5;
  const int b = bh >> 3, h = bh & 7;
  const int t = threadIdx.x, wid = t >> 6, lane = t & 63;
  const int qg = wid & 1, ks = wid >> 1;
  const int c = lane & 31, hi = lane >> 5;
  const int hsh = hi * 4;
  const int qrow = qt * 128 + qg * 64 + c;   // tile A; tile B = qrow+32

  const uint16_t* Qbh = args.Q[j] + (size_t)(b * 8 + h) * 32768;
  const uint16_t* Kbh = args.K[j] + (size_t)(b * 8 + h) * 32768;
  const uint16_t* Vbh = args.Vt[j] + ((size_t)(b * 8 + h) * 32 + c) * 1024 + hi * 8;

  const bf16x8 qa0 = *(const bf16x8*)&Qbh[qrow * 32 + hi * 8];
  const bf16x8 qa1 = *(const bf16x8*)&Qbh[qrow * 32 + 16 + hi * 8];
  const bf16x8 qb0 = *(const bf16x8*)&Qbh[(qrow + 32) * 32 + hi * 8];
  const bf16x8 qb1 = *(const bf16x8*)&Qbh[(qrow + 32) * 32 + 16 + hi * 8];

  f32x16 oA = {}, oB = {};
  float lA = 0.f, lB = 0.f;

  const int kbeg = ks * 512;
  const uint16_t* kp = Kbh + (size_t)(kbeg + c) * 32 + hi * 8;
  const uint16_t* vp = Vbh + kbeg;
  const uint32_t* ap = args.adjb[j] + (size_t)b * 32768
                       + ((size_t)(kbeg >> 5) << 10) + qrow;

  for (int it = 0; it < 16; ++it) {
    const uint32_t wA = ap[0]  >> hsh;
    const uint32_t wB = ap[32] >> hsh;
    const bf16x8 kf0 = *(const bf16x8*)kp;
    const bf16x8 kf1 = *(const bf16x8*)(kp + 16);
    const bf16x8 vf0 = *(const bf16x8*)vp;
    const bf16x8 vf1 = *(const bf16x8*)(vp + 16);
    ap += 1024; kp += 1024; vp += 32;

    f32x16 sA = {}, sB = {};
    sA = __builtin_amdgcn_mfma_f32_32x32x16_bf16(kf0, qa0, sA, 0, 0, 0);
    sA = __builtin_amdgcn_mfma_f32_32x32x16_bf16(kf1, qa1, sA, 0, 0, 0);
    sB = __builtin_amdgcn_mfma_f32_32x32x16_bf16(kf0, qb0, sB, 0, 0, 0);
    sB = __builtin_amdgcn_mfma_f32_32x32x16_bf16(kf1, qb1, sB, 0, 0, 0);

    soft_pv(sA, wA, lA, vf0, vf1, oA);
    soft_pv(sB, wB, lB, vf0, vf1, oB);
  }

  // ---- split-K combine (zero-shift partials add directly) -----------------
  __shared__ float red[2][2][64][17];
  if (ks == 1) {
    #pragma unroll
    for (int r = 0; r < 16; ++r) {
      red[qg][0][lane][r] = oA[r];
      red[qg][1][lane][r] = oB[r];
    }
    red[qg][0][lane][16] = lA;
    red[qg][1][lane][16] = lB;
  }
  __syncthreads();
  if (ks == 1) return;

  {
    #pragma unroll
    for (int r = 0; r < 16; ++r) {
      oA[r] += red[qg][0][lane][r];
      oB[r] += red[qg][1][lane][r];
    }
    lA += red[qg][0][lane][16];
    lB += red[qg][1][lane][16];
  }

  lA += __shfl_xor(lA, 32, 64);
  lB += __shfl_xor(lB, 32, 64);
  const float invA = 1.0f / lA;
  const float invB = 1.0f / lB;
  uint16_t* O = args.O[j];
  const size_t obA = (size_t)(b * 1024 + qrow) * 256 + h * 32 + 4 * hi;
  const size_t obB = obA + (size_t)32 * 256;
  #pragma unroll
  for (int rq = 0; rq < 4; ++rq) {
    uint2 vA, vB;
    vA.x = packbf2(oA[4*rq+0] * invA, oA[4*rq+1] * invA);
    vA.y = packbf2(oA[4*rq+2] * invA, oA[4*rq+3] * invA);
    vB.x = packbf2(oB[4*rq+0] * invB, oB[4*rq+1] * invB);
    vB.y = packbf2(oB[4*rq+2] * invB, oB[4*rq+3] * invB);
    *(uint2*)&O[obA + 8 * rq] = vA;
    *(uint2*)&O[obB + 8 * rq] = vB;
  }
}

// ---------------------------------------------------------------------------
// Fused LayerNorm(x0)+LayerNorm(x1) -> relu(sum) (+ optional fp32 residual).
// x0/x1 bf16.  Writes fp32 out and/or bf16 mirror (either may be null).
// ---------------------------------------------------------------------------
struct LnArgs {
  const uint16_t* x0; const uint16_t* x1;
  const float* g0; const float* be0;
  const float* g1; const float* be1;
  const float* addin;
  float* out;
  uint16_t* outbf;
};
struct LnBoth { LnArgs p[2]; };

__global__ __launch_bounds__(256) void ln_k(LnBoth args) {
  const LnArgs a = args.p[blockIdx.z];
  const int wid = threadIdx.x >> 6, lane = threadIdx.x & 63;
  const int row = blockIdx.x * 4 + wid;
  const size_t off = (size_t)row * 256 + lane * 4;

  const uint2 u0 = *(const uint2*)(a.x0 + off);
  const uint2 u1 = *(const uint2*)(a.x1 + off);
  float4 x0, x1;
  x0.x = bf2f((uint16_t)u0.x); x0.y = bf2f((uint16_t)(u0.x >> 16));
  x0.z = bf2f((uint16_t)u0.y); x0.w = bf2f((uint16_t)(u0.y >> 16));
  x1.x = bf2f((uint16_t)u1.x); x1.y = bf2f((uint16_t)(u1.x >> 16));
  x1.z = bf2f((uint16_t)u1.y); x1.w = bf2f((uint16_t)(u1.y >> 16));

  float s0 = x0.x + x0.y + x0.z + x0.w;
  float s1 = x1.x + x1.y + x1.z + x1.w;
  #pragma unroll
  for (int s = 1; s < 64; s <<= 1) { s0 += __shfl_xor(s0, s, 64); s1 += __shfl_xor(s1, s, 64); }
  const float mu0 = s0 * (1.f / 256.f), mu1 = s1 * (1.f / 256.f);
  const float d0x = x0.x - mu0, d0y = x0.y - mu0, d0z = x0.z - mu0, d0w = x0.w - mu0;
  const float d1x = x1.x - mu1, d1y = x1.y - mu1, d1z = x1.z - mu1, d1w = x1.w - mu1;
  float v0 = d0x * d0x + d0y * d0y + d0z * d0z + d0w * d0w;
  float v1 = d1x * d1x + d1y * d1y + d1z * d1z + d1w * d1w;
  #pragma unroll
  for (int s = 1; s < 64; s <<= 1) { v0 += __shfl_xor(v0, s, 64); v1 += __shfl_xor(v1, s, 64); }
  const float r0 = rsqrtf(v0 * (1.f / 256.f) + 1e-5f);
  const float r1 = rsqrtf(v1 * (1.f / 256.f) + 1e-5f);

  const size_t po = (size_t)lane * 4;
  const float4 g0 = *(const float4*)(a.g0 + po), b0 = *(const float4*)(a.be0 + po);
  const float4 g1 = *(const float4*)(a.g1 + po), b1 = *(const float4*)(a.be1 + po);

  float4 y;
  y.x = fmaxf(d0x * r0 * g0.x + b0.x + d1x * r1 * g1.x + b1.x, 0.f);
  y.y = fmaxf(d0y * r0 * g0.y + b0.y + d1y * r1 * g1.y + b1.y, 0.f);
  y.z = fmaxf(d0z * r0 * g0.z + b0.z + d1z * r1 * g1.z + b1.z, 0.f);
  y.w = fmaxf(d0w * r0 * g0.w + b0.w + d1w * r1 * g1.w + b1.w, 0.f);
  if (a.addin) {
    const float4 ad = *(const float4*)(a.addin + off);
    y.x += ad.x; y.y += ad.y; y.z += ad.z; y.w += ad.w;
  }
  if (a.out) *(float4*)(a.out + off) = y;
  if (a.outbf) {
    uint2 vb;
    vb.x = packbf2(y.x, y.y); vb.y = packbf2(y.z, y.w);
    *(uint2*)(a.outbf + off) = vb;
  }
}

// ---------------------------------------------------------------------------
// Host launch
// ---------------------------------------------------------------------------
extern "C" void kernel_launch(void* const* d_in, const int* in_sizes, int n_in,
                              void* d_out, int out_size, void* d_ws, size_t ws_size,
                              hipStream_t stream) {
  (void)in_sizes; (void)n_in; (void)out_size; (void)ws_size;
  const float* h_a = (const float*)d_in[0];
  const float* h_b = (const float*)d_in[1];
  const float* bq  = (const float*)d_in[7];
  const float* bk  = (const float*)d_in[9];
  const float* bv  = (const float*)d_in[11];
  const float* bo  = (const float*)d_in[13];
  const float* lng = (const float*)d_in[14];
  const float* lnb = (const float*)d_in[15];

  // log2(e)/sqrt(dk): folds softmax scale + exp->exp2 into Q projection
  const float QSC = 1.4426950408889634f * 0.17677669529663687f;

  char* ws = (char*)d_ws;
  uint16_t* WT   = (uint16_t*)ws;                        // 0-4 MB
  uint32_t* ADJB = (uint32_t*)(ws + (4u  << 20));        // 4-6 MB (transposed)
  uint16_t* hAbf = (uint16_t*)(ws + (6u  << 20));        // 6-8 MB
  uint16_t* hBbf = (uint16_t*)(ws + (8u  << 20));        // 8-10 MB
  uint16_t* Qb[4]; uint16_t* Kb[4]; uint16_t* Vtb[4]; uint16_t* ATb[4]; uint16_t* MOb[4];
  for (int j = 0; j < 4; ++j) {
    Qb[j]  = (uint16_t*)(ws + (10u << 20) + (size_t)j * (2u << 20));  // 10-18
    Kb[j]  = (uint16_t*)(ws + (18u << 20) + (size_t)j * (2u << 20));  // 18-26
    Vtb[j] = (uint16_t*)(ws + (26u << 20) + (size_t)j * (2u << 20));  // 26-34
    ATb[j] = (uint16_t*)(ws + (34u << 20) + (size_t)j * (2u << 20));  // 34-42
    MOb[j] = (uint16_t*)(ws + (42u << 20) + (size_t)j * (2u << 20));  // 42-50
  }

  wprep_k<<<dim3(4, 4, 32), 256, 0, stream>>>(
      (const float*)d_in[6], (const float*)d_in[8],
      (const float*)d_in[10], (const float*)d_in[12], WT);
  cvt_k<<<dim3(512, 2), 256, 0, stream>>>(h_a, h_b, hAbf, hBbf);
  {
    AdjArgs aa;
    for (int j = 0; j < 4; ++j) {
      aa.adj[j]  = (const int*)d_in[2 + j];
      aa.bits[j] = ADJB + (size_t)j * 131072;
    }
    adjbits_k<<<dim3(16384, 1, 4), 256, 0, stream>>>(aa);
  }

  for (int i = 0; i < 2; ++i) {
    const uint16_t* qbf[4]  = { hAbf, hBbf, hBbf, hAbf };   // a2a, b2b, a2b, b2a
    const uint16_t* kvbf[4] = { hAbf, hBbf, hAbf, hBbf };

    {
      GemmArgs ga = {};
      for (int j = 0; j < 4; ++j) {
        const int mm = i * 4 + j;
        ga.A[j]     = qbf[j];  ga.W[j]     = WT + 0 * 524288 + (size_t)mm * 65536;
        ga.bias[j]  = bq + mm * 256; ga.C[j] = Qb[j];  ga.os[j] = QSC;  ga.mode[j] = 2;
        ga.A[4+j]   = kvbf[j]; ga.W[4+j]   = WT + 1 * 524288 + (size_t)mm * 65536;
        ga.bias[4+j]= bk + mm * 256; ga.C[4+j] = Kb[j]; ga.os[4+j] = 1.0f; ga.mode[4+j] = 2;
        ga.A[8+j]   = kvbf[j]; ga.W[8+j]   = WT + 2 * 524288 + (size_t)mm * 65536;
        ga.bias[8+j]= bv + mm * 256; ga.C[8+j] = Vtb[j]; ga.os[8+j] = 1.0f; ga.mode[8+j] = 3;
      }
      gemm_k<<<dim3(2, 32, 12), 256, 0, stream>>>(ga);
    }
    {
      AttnArgs at;
      for (int j = 0; j < 4; ++j) {
        at.Q[j] = Qb[j]; at.K[j] = Kb[j]; at.Vt[j] = Vtb[j];
        at.adjb[j] = ADJB + (size_t)j * 131072; at.O[j] = ATb[j];
      }
      attn_k<<<dim3(1024, 1, 1), 256, 0, stream>>>(at);
    }
    {
      GemmArgs go = {};
      for (int j = 0; j < 4; ++j) {
        const int mm = i * 4 + j;
        go.A[j] = ATb[j]; go.W[j] = WT + 3 * 524288 + (size_t)mm * 65536;
        go.bias[j] = bo + mm * 256; go.res[j] = qbf[j]; go.C[j] = MOb[j];
        go.os[j] = 1.0f; go.mode[j] = 1;
      }
      gemm_k<<<dim3(2, 32, 4), 256, 0, stream>>>(go);
    }
    {
      LnBoth lb;
      float* outA = (i == 1) ? (float*)d_out : nullptr;
      float* outB = (i == 1) ? ((float*)d_out + 1048576) : nullptr;
      const float* addA = (i == 1) ? h_a : nullptr;
      const float* addB = (i == 1) ? h_b : nullptr;
      uint16_t* mbA = (i == 0) ? hAbf : nullptr;   // bf16 mirror for next layer
      uint16_t* mbB = (i == 0) ? hBbf : nullptr;
      lb.p[0] = { MOb[0], MOb[3],
                  lng + (i * 4 + 0) * 256, lnb + (i * 4 + 0) * 256,
                  lng + (i * 4 + 3) * 256, lnb + (i * 4 + 3) * 256,
                  addA, outA, mbA };
      lb.p[1] = { MOb[1], MOb[2],
                  lng + (i * 4 + 1) * 256, lnb + (i * 4 + 1) * 256,
                  lng + (i * 4 + 2) * 256, lnb + (i * 4 + 2) * 256,
                  addB, outB, mbB };
      ln_k<<<dim3(1024, 1, 2), 256, 0, stream>>>(lb);
    }
  }
}